// Round 5
// baseline (2908.625 us; speedup 1.0000x reference)
//
#include <hip/hip_runtime.h>
#include <hip/hip_fp16.h>
#include <hip/hip_bf16.h>

#define B_ 16
#define N_ 64
#define T_ 32
#define D_ 512
#define H_ 256
#define K_ 13
#define S_ 2048
#define G4_ 1024

typedef float f32x4 __attribute__((ext_vector_type(4)));
typedef short s16x8 __attribute__((ext_vector_type(8)));
typedef int   i32x4 __attribute__((ext_vector_type(4)));

#define INVQ 2.0505324e-5f   /* 1/(384*127) */

// barrier with LDS-only drain: do NOT wait vmcnt (global loads/stores stay in flight)
#define BAR() do { \
  asm volatile("s_waitcnt lgkmcnt(0)" ::: "memory"); \
  __builtin_amdgcn_s_barrier(); \
  __builtin_amdgcn_sched_barrier(0); \
} while (0)

__device__ __forceinline__ float sigm(float x){ return 1.0f/(1.0f+__expf(-x)); }
__device__ __forceinline__ float tanh_fast(float x){ return 1.0f - 2.0f/(1.0f+__expf(2.0f*x)); }

// ---------- prefix sums over segment lengths ----------
__global__ void k_prep(const int* __restrict__ length, int* __restrict__ cum, int* __restrict__ doc){
  const int b = threadIdx.x >> 6, n = threadIdx.x & 63;
  const int v = length[b*N_ + n];
  int x = v;
  #pragma unroll
  for (int d = 1; d < 64; d <<= 1){
    int y = __shfl_up(x, d);
    if (n >= d) x += y;
  }
  cum[b*N_ + n] = x - v;          // exclusive
  if (n == 63) doc[b] = x;        // doc_len
}

// ---------- cast weights: w_ih -> bf16 [2048][512]; w_hh -> i8 [dir][1024][256] ----------
__global__ __launch_bounds__(256) void k_cast(const float* __restrict__ wf, const float* __restrict__ wb,
                       const float* __restrict__ hf, const float* __restrict__ hb,
                       ushort* __restrict__ wih, signed char* __restrict__ whh8){
  const int i = blockIdx.x*256 + threadIdx.x;
  if (i < 2*G4_*D_){
    const int dir = i / (G4_*D_); const int r = i % (G4_*D_);
    const float v = dir ? wb[r] : wf[r];
    ((__hip_bfloat16*)wih)[i] = __float2bfloat16(v);
  } else {
    const int j2 = i - 2*G4_*D_;
    if (j2 < 2*G4_*H_){
      const int dir = j2 >> 18; const int r = j2 & 262143;
      const float v = (dir ? hb : hf)[r];
      int q = (int)rintf(v * 384.0f);
      whh8[j2] = (signed char)min(127, max(-127, q));
    }
  }
}

// ---------- scatter source map + packed tags ----------
__global__ __launch_bounds__(256) void k_srcmap(const int* __restrict__ length, const int* __restrict__ cum,
                         const int* __restrict__ tags, int* __restrict__ src, int* __restrict__ ntag){
  const int i = blockIdx.x*256 + threadIdx.x;            // B*N*T = 32768
  const int b = i >> 11, nt = i & 2047, n = nt >> 5, t = nt & 31;
  if (t < length[b*N_ + n]){
    const int dest = cum[b*N_ + n] + t;
    src[b*S_ + dest] = nt;
    ntag[b*S_ + dest] = tags[i];
  }
}

// ---------- build packed new_x (bf16) + mask output ----------
__global__ __launch_bounds__(256) void k_newx(const float* __restrict__ x, const float* __restrict__ gcn,
                      const int* __restrict__ src, const int* __restrict__ doc,
                      ushort* __restrict__ nx, float* __restrict__ mask_out){
  const int r = blockIdx.x; const int b = r >> 11, s = r & 2047;
  const int L = doc[b];
  const int d = threadIdx.x*2;
  const float2 g2 = *(const float2*)&gcn[((size_t)(b*N_ + (s>>5)))*D_ + d];
  float v0 = g2.x, v1 = g2.y;
  if (s < L){
    const int nt = src[r];
    const float2 x2 = *(const float2*)&x[((size_t)(b*S_ + nt))*D_ + d];
    v0 += x2.x; v1 += x2.y;
  }
  __hip_bfloat16* o = (__hip_bfloat16*)nx + (size_t)r*D_ + d;
  o[0] = __float2bfloat16(v0); o[1] = __float2bfloat16(v1);
  if (threadIdx.x == 0) mask_out[r] = (s < L) ? 1.0f : 0.0f;
}

// ---------- input projection GEMM: pre[b][s][dir*1024+g*256+u] (f16), bias added ----------
__global__ __launch_bounds__(256) void k_gemm(const ushort* __restrict__ A, const ushort* __restrict__ Bw,
    const float* __restrict__ bias_f, const float* __restrict__ bias_b,
    const int* __restrict__ doc, __half* __restrict__ pre){
  const int m0 = blockIdx.x*128, n0 = blockIdx.y*128;
  const int b = m0 >> 11, s0 = m0 & 2047;
  if (s0 >= doc[b]) return;
  __shared__ __align__(16) ushort la[128*40];
  __shared__ __align__(16) ushort lb[128*40];
  const int tid = threadIdx.x, lane = tid & 63, w = tid >> 6;
  const int wr = w >> 1, wc = w & 1;
  const int fr = lane & 15, fq = lane >> 4;
  f32x4 acc[4][4] = {};
  const int srow = tid >> 1;
  const int sko  = (tid & 1)*16;
  for (int kt = 0; kt < 16; ++kt){
    const int k0 = kt*32;
    const float4 a0 = *(const float4*)&A[(size_t)(m0+srow)*512 + k0 + sko];
    const float4 a1 = *(const float4*)&A[(size_t)(m0+srow)*512 + k0 + sko + 8];
    const float4 b0 = *(const float4*)&Bw[(size_t)(n0+srow)*512 + k0 + sko];
    const float4 b1 = *(const float4*)&Bw[(size_t)(n0+srow)*512 + k0 + sko + 8];
    *(float4*)&la[srow*40 + sko]     = a0;
    *(float4*)&la[srow*40 + sko + 8] = a1;
    *(float4*)&lb[srow*40 + sko]     = b0;
    *(float4*)&lb[srow*40 + sko + 8] = b1;
    __syncthreads();
    s16x8 af[4], bfr[4];
    #pragma unroll
    for (int mi=0; mi<4; ++mi) af[mi] = *(const s16x8*)&la[(wr*64+mi*16+fr)*40 + fq*8];
    #pragma unroll
    for (int ni=0; ni<4; ++ni) bfr[ni] = *(const s16x8*)&lb[(wc*64+ni*16+fr)*40 + fq*8];
    #pragma unroll
    for (int mi=0; mi<4; ++mi){
      #pragma unroll
      for (int ni=0; ni<4; ++ni){
        acc[mi][ni] = __builtin_amdgcn_mfma_f32_16x16x32_bf16(af[mi], bfr[ni], acc[mi][ni], 0, 0, 0);
      }
    }
    __syncthreads();
  }
  #pragma unroll
  for (int ni=0; ni<4; ++ni){
    const int n = n0 + wc*64 + ni*16 + fr;
    const float bv = (n < 1024) ? bias_f[n] : bias_b[n-1024];
    #pragma unroll
    for (int mi=0; mi<4; ++mi){
      const int mb = m0 + wr*64 + mi*16 + fq*4;
      #pragma unroll
      for (int j=0; j<4; ++j)
        pre[(size_t)(mb+j)*2048 + n] = __float2half(acc[mi][ni][j] + bv);
    }
  }
}

// ---------- recurrent LSTM: m=4 chains/block (same dir), 2-group MFMA/VALU stagger ----------
// grid = 8: blockIdx = q*2 + dir, chains = batches q*4..q*4+3, direction dir.
// 512 threads = 8 waves; wave wv owns units [wv*32, wv*32+32) x 4 gates for both groups.
__global__ __launch_bounds__(512, 2) void k_recur5(
    const signed char* __restrict__ W8,
    const __half* __restrict__ pre, const int* __restrict__ doc,
    __half* __restrict__ outh)
{
  const int q = blockIdx.x >> 1, dir = blockIdx.x & 1;
  const int tid = threadIdx.x, lane = tid & 63, wv = tid >> 6;
  const int fr = lane & 15;
  const int cl = lane >> 5;            // chain-of-group this lane owns in gate phase
  const int ul = lane & 31;            // unit-local within wave
  const int u  = wv*32 + ul;           // global unit

  __shared__ __align__(16) signed char hq[2][2][2][256]; // [grp][buf][chain][unit] i8
  __shared__ __align__(16) int rsc[8][4][32][2];         // [wave][gate][u_loc][chain] redistribution

  // zero h buffers (2 KB)
  ((unsigned*)hq)[tid] = 0u;

  const int b1 = q*4 + cl;             // G1 chain of this lane
  const int b2 = q*4 + 2 + cl;         // G2 chain of this lane
  const int L1 = doc[b1], L2 = doc[b2];
  int Lblk = 0;
  #pragma unroll
  for (int j = 0; j < 4; ++j) Lblk = max(Lblk, doc[q*4+j]);

  // W_hh i8 B-fragments: lane holds W[row=g*256+wv*32+nt*16+fr][kt*64+(lane>>4)*16 ..+16]
  i32x4 wfrag[2][4][4];
  #pragma unroll
  for (int nt = 0; nt < 2; ++nt)
    #pragma unroll
    for (int g = 0; g < 4; ++g){
      const int row = g*256 + wv*32 + nt*16 + fr;
      #pragma unroll
      for (int kt = 0; kt < 4; ++kt)
        wfrag[nt][g][kt] = *(const i32x4*)&W8[(size_t)dir*262144 + (size_t)row*256 + kt*64 + (lane>>4)*16];
    }

  i32x4 af[4]  = {{0,0,0,0},{0,0,0,0},{0,0,0,0},{0,0,0,0}};   // persistent-zero A frags
  i32x4 accA[2][4] = {};   // G1 accumulators
  i32x4 accB[2][4] = {};   // G2 accumulators (zero == W*h_{-1})

  // per-lane pre/out base pointers (pre col = dir*1024 + g*256 + u; g via imm offset)
  const __half* pb1 = pre + (size_t)b1*S_*2048 + dir*1024 + u;
  const __half* pb2 = pre + (size_t)b2*S_*2048 + dir*1024 + u;
  __half* ob1 = outh + (size_t)b1*S_*512 + dir*256 + u;
  __half* ob2 = outh + (size_t)b2*S_*512 + dir*256 + u;

  float c1s = 0.f, c2s = 0.f;
  BAR();

  for (int t = 0; t < Lblk; ++t){
    const int buf = t & 1, nbuf = buf ^ 1;
    const int pos1 = dir ? max(L1-1-t, 0) : t;
    const int pos2 = dir ? max(L2-1-t, 0) : t;

    // early-issue pre-activation loads for BOTH groups (consumed under the matrix waits)
    __half pg1[4], pg2[4];
    {
      const __half* p2 = pb2 + (size_t)pos2*2048;
      const __half* p1 = pb1 + (size_t)pos1*2048;
      #pragma unroll
      for (int g = 0; g < 4; ++g) pg2[g] = p2[g*256];
      #pragma unroll
      for (int g = 0; g < 4; ++g) pg1[g] = p1[g*256];
    }

    // ================= half A =================
    // issue G1 MFMAs (h_G1[t-1] from hq[0][buf])
    if (fr < 2){
      #pragma unroll
      for (int kt = 0; kt < 4; ++kt)
        af[kt] = *(const i32x4*)&hq[0][buf][fr][kt*64 + (lane>>4)*16];
    }
    #pragma unroll
    for (int kt = 0; kt < 4; ++kt)
      #pragma unroll
      for (int nt = 0; nt < 2; ++nt)
        #pragma unroll
        for (int g = 0; g < 4; ++g)
          accA[nt][g] = __builtin_amdgcn_mfma_i32_16x16x64_i8(af[kt], wfrag[nt][g][kt], accA[nt][g], 0, 0, 0);

    // redistribute G2 accumulators (finished last half) to all 64 lanes
    if (lane < 16){
      #pragma unroll
      for (int nt = 0; nt < 2; ++nt)
        #pragma unroll
        for (int g = 0; g < 4; ++g){
          int2 v; v.x = accB[nt][g][0]; v.y = accB[nt][g][1];
          *(int2*)&rsc[wv][g][nt*16 + fr][0] = v;
        }
    }
    #pragma unroll
    for (int nt = 0; nt < 2; ++nt)
      #pragma unroll
      for (int g = 0; g < 4; ++g)
        accB[nt][g] = (i32x4){0,0,0,0};

    // gates G2 -> h_G2[t]
    {
      float gv[4];
      #pragma unroll
      for (int g = 0; g < 4; ++g)
        gv[g] = (float)rsc[wv][g][ul][cl]*INVQ + __half2float(pg2[g]);
      const float c = sigm(gv[1])*c2s + sigm(gv[0])*tanh_fast(gv[2]);
      c2s = c;
      const float h = sigm(gv[3])*tanh_fast(c);
      int q8 = (int)rintf(h*127.0f);
      q8 = min(127, max(-127, q8));
      hq[1][nbuf][cl][u] = (signed char)q8;
      if (t < L2) ob2[(size_t)pos2*512] = __float2half(h);
    }
    BAR();

    // ================= half B =================
    // issue G2 MFMAs (h_G2[t] from hq[1][nbuf])
    if (fr < 2){
      #pragma unroll
      for (int kt = 0; kt < 4; ++kt)
        af[kt] = *(const i32x4*)&hq[1][nbuf][fr][kt*64 + (lane>>4)*16];
    }
    #pragma unroll
    for (int kt = 0; kt < 4; ++kt)
      #pragma unroll
      for (int nt = 0; nt < 2; ++nt)
        #pragma unroll
        for (int g = 0; g < 4; ++g)
          accB[nt][g] = __builtin_amdgcn_mfma_i32_16x16x64_i8(af[kt], wfrag[nt][g][kt], accB[nt][g], 0, 0, 0);

    // redistribute G1 accumulators (stall here is covered by G2's matrix backlog)
    if (lane < 16){
      #pragma unroll
      for (int nt = 0; nt < 2; ++nt)
        #pragma unroll
        for (int g = 0; g < 4; ++g){
          int2 v; v.x = accA[nt][g][0]; v.y = accA[nt][g][1];
          *(int2*)&rsc[wv][g][nt*16 + fr][0] = v;
        }
    }
    #pragma unroll
    for (int nt = 0; nt < 2; ++nt)
      #pragma unroll
      for (int g = 0; g < 4; ++g)
        accA[nt][g] = (i32x4){0,0,0,0};

    // gates G1 -> h_G1[t]
    {
      float gv[4];
      #pragma unroll
      for (int g = 0; g < 4; ++g)
        gv[g] = (float)rsc[wv][g][ul][cl]*INVQ + __half2float(pg1[g]);
      const float c = sigm(gv[1])*c1s + sigm(gv[0])*tanh_fast(gv[2]);
      c1s = c;
      const float h = sigm(gv[3])*tanh_fast(c);
      int q8 = (int)rintf(h*127.0f);
      q8 = min(127, max(-127, q8));
      hq[0][nbuf][cl][u] = (signed char)q8;
      if (t < L1) ob1[(size_t)pos1*512] = __float2half(h);
    }
    BAR();
  }
}

// ---------- logits: wave per row (outh is f16 now) ----------
__global__ __launch_bounds__(256) void k_logits(const __half* __restrict__ outh, const float* __restrict__ mw,
    const float* __restrict__ mb, const int* __restrict__ doc, float* __restrict__ logits){
  const int w = threadIdx.x >> 6, lane = threadIdx.x & 63;
  const int r = blockIdx.x*4 + w;
  const int b = r >> 11, s = r & 2047;
  if (s >= doc[b]){
    if (lane < 13) logits[(size_t)r*13 + lane] = mb[lane];
    return;
  }
  float xv[8];
  #pragma unroll
  for (int m=0; m<8; ++m) xv[m] = __half2float(outh[(size_t)r*512 + lane + m*64]);
  #pragma unroll
  for (int k=0; k<13; ++k){
    float p = 0.f;
    #pragma unroll
    for (int m=0; m<8; ++m) p += xv[m]*mw[k*512 + lane + m*64];
    #pragma unroll
    for (int off=32; off; off>>=1) p += __shfl_down(p, off);
    if (lane == 0) logits[(size_t)r*13 + k] = p + mb[k];
  }
}

// ---------- CRF: one wave per batch ----------
__global__ void k_crf(const float* __restrict__ logits, const int* __restrict__ ntag,
    const int* __restrict__ doc, const float* __restrict__ trans,
    const float* __restrict__ stt, const float* __restrict__ ent, float* __restrict__ ll){
  const int b = blockIdx.x, lane = threadIdx.x;
  const int L = doc[b];
  const float* lg = logits + (size_t)b*S_*13;
  float tc[13];
  #pragma unroll
  for (int i=0; i<13; ++i) tc[i] = (lane < 13) ? trans[i*13 + lane] : 0.f;
  float alpha = (lane < 13) ? (stt[lane] + lg[lane]) : -1e30f;
  for (int t=1; t<L; ++t){
    const float e = (lane < 13) ? lg[(size_t)t*13 + lane] : 0.f;
    float v[13]; float m = -1e30f;
    #pragma unroll
    for (int i=0; i<13; ++i){ v[i] = __shfl(alpha, i) + tc[i]; m = fmaxf(m, v[i]); }
    float sum = 0.f;
    #pragma unroll
    for (int i=0; i<13; ++i) sum += __expf(v[i] - m);
    alpha = m + __logf(sum) + e;
  }
  float av = (lane < 13) ? alpha + ent[lane] : -1e30f;
  float m2 = -1e30f;
  #pragma unroll
  for (int i=0; i<13; ++i) m2 = fmaxf(m2, __shfl(av, i));
  float s2 = 0.f;
  #pragma unroll
  for (int i=0; i<13; ++i) s2 += __expf(__shfl(av, i) - m2);
  const float logz = m2 + __logf(s2);
  const int* tg = ntag + (size_t)b*S_;
  float num = 0.f;
  for (int t = lane; t < L; t += 64){
    const int cur = tg[t];
    num += lg[(size_t)t*13 + cur];
    if (t >= 1) num += trans[tg[t-1]*13 + cur];
  }
  #pragma unroll
  for (int off=32; off; off>>=1) num += __shfl_down(num, off);
  if (lane == 0){
    num += stt[tg[0]] + ent[tg[L-1]];
    ll[b] = num - logz;
  }
}

extern "C" void kernel_launch(void* const* d_in, const int* in_sizes, int n_in,
                              void* d_out, int out_size, void* d_ws, size_t ws_size,
                              hipStream_t stream){
  const float* x    = (const float*)d_in[0];
  const float* gcn  = (const float*)d_in[1];
  const int* length = (const int*)d_in[3];
  const int* tags   = (const int*)d_in[4];
  const float* wihf = (const float*)d_in[5];
  const float* whhf = (const float*)d_in[6];
  const float* bf   = (const float*)d_in[7];
  const float* wihb = (const float*)d_in[8];
  const float* whhb = (const float*)d_in[9];
  const float* bb   = (const float*)d_in[10];
  const float* mw   = (const float*)d_in[11];
  const float* mb   = (const float*)d_in[12];
  const float* trans= (const float*)d_in[13];
  const float* stt  = (const float*)d_in[14];
  const float* ent  = (const float*)d_in[15];

  char* ws = (char*)d_ws;
  ushort* nx   = (ushort*)(ws + 0);              // 33,554,432 B  new_x bf16
  __half* pre  = (__half*)(ws + 33554432);       // 134,217,728 B pre-activations f16
  __half* outh = (__half*)(ws + 167772160);      // 33,554,432 B  concat h states (f16)
  ushort* wih  = (ushort*)(ws + 234881024);      // 2,097,152 B   w_ih bf16 [2048][512]
  signed char* whh8 = (signed char*)(ws + 236978176); // 524,288 B w_hh i8 [2][1024][256]
  int*    src  = (int*)(ws + 238026752);         // 131,072 B
  int*    ntag = (int*)(ws + 238157824);         // 131,072 B
  int*    cum  = (int*)(ws + 238288896);         // 4,096 B
  int*    doc  = (int*)(ws + 238292992);         // 64 B

  float* logits  = (float*)d_out;                // 425,984 floats
  float* maskout = logits + 425984;              // 32,768 floats
  float* ll      = maskout + 32768;              // 16 floats

  hipLaunchKernelGGL(k_prep,   dim3(1),        dim3(1024), 0, stream, length, cum, doc);
  hipLaunchKernelGGL(k_cast,   dim3(6144),     dim3(256),  0, stream, wihf, wihb, whhf, whhb, wih, whh8);
  hipLaunchKernelGGL(k_srcmap, dim3(128),      dim3(256),  0, stream, length, cum, tags, src, ntag);
  hipLaunchKernelGGL(k_newx,   dim3(32768),    dim3(256),  0, stream, x, gcn, src, doc, nx, maskout);
  hipLaunchKernelGGL(k_gemm,   dim3(256, 16),  dim3(256),  0, stream, nx, wih, bf, bb, doc, pre);
  hipLaunchKernelGGL(k_recur5, dim3(8),        dim3(512),  0, stream, whh8, pre, doc, outh);
  hipLaunchKernelGGL(k_logits, dim3(8192),     dim3(256),  0, stream, outh, mw, mb, doc, logits);
  hipLaunchKernelGGL(k_crf,    dim3(16),       dim3(64),   0, stream, logits, ntag, doc, trans, stt, ent, ll);
}